// Round 1
// baseline (356.442 us; speedup 1.0000x reference)
//
#include <hip/hip_runtime.h>
#include <hip/hip_bf16.h>

// Problem: N=64 batches, IO=64, H=1024, S=512
#define IOdim 64
#define Hdim  1024
#define Sdim  512
#define Nbat  64

typedef __bf16 bf16x8_t __attribute__((ext_vector_type(8)));
typedef float  f32x4_t  __attribute__((ext_vector_type(4)));

#define MFMA16(a, b, c) __builtin_amdgcn_mfma_f32_16x16x32_bf16((a), (b), (c), 0, 0, 0)

__device__ __forceinline__ unsigned short f2bf(float f) {
    return __builtin_bit_cast(unsigned short, (__bf16)f);
}

// ---------------------------------------------------------------------------
// Prep: fp32 -> bf16 elementwise (output_set, 65536 elems)
__global__ __launch_bounds__(256) void cvt_kernel(const float* __restrict__ in,
                                                  unsigned short* __restrict__ outp,
                                                  int nElem) {
    int idx = blockIdx.x * 256 + threadIdx.x;
    if (idx < nElem) outp[idx] = f2bf(in[idx]);
}

// Prep: transpose fp32 [R][C] -> bf16 [C][R] (LDS 32x32 tiles)
__global__ __launch_bounds__(256) void transpose_cvt(const float* __restrict__ in,
                                                     unsigned short* __restrict__ outp,
                                                     int R, int C) {
    __shared__ float tile[32][33];
    int c0 = blockIdx.x * 32, r0 = blockIdx.y * 32;
    int tx = threadIdx.x, ty = threadIdx.y; // 32 x 8
#pragma unroll
    for (int i = 0; i < 4; i++) {
        int r = ty + i * 8;
        tile[r][tx] = in[(size_t)(r0 + r) * C + c0 + tx];
    }
    __syncthreads();
#pragma unroll
    for (int i = 0; i < 4; i++) {
        int r = ty + i * 8;
        outp[(size_t)(c0 + r) * R + r0 + tx] = f2bf(tile[tx][r]);
    }
}

// ---------------------------------------------------------------------------
// scores: attn[n][i][s] = sum_h output_set[i][h] * states[n][s][h]
// Block: 256 thr (4 waves), covers n=blockIdx.y, s-tile 64 (wave -> 16 s), all 64 i.
// A (output_set bf16) staged in LDS per 32-k chunk; B built inline from fp32 states.
__global__ __launch_bounds__(256) void scores_kernel(const float* __restrict__ states,
                                                     const unsigned short* __restrict__ osb,
                                                     float* __restrict__ attnf) {
    __shared__ unsigned short Alds[64 * 40];
    int n = blockIdx.y;
    int tid = threadIdx.x, lane = tid & 63, g = tid >> 6; // g = wave id
    int col = lane & 15, quad = lane >> 4;
    int s = blockIdx.x * 64 + g * 16 + col;
    const float* srow = states + (n * Sdim + s) * Hdim + quad * 8;
    f32x4_t acc0 = {0,0,0,0}, acc1 = {0,0,0,0}, acc2 = {0,0,0,0}, acc3 = {0,0,0,0};
    for (int kc = 0; kc < Hdim; kc += 32) {
        // stage A chunk: rows i=lane (64), k-seg g*8..g*8+7  (16B per thread)
        uint4 av = *(const uint4*)(osb + lane * Hdim + kc + g * 8);
        *(uint4*)(Alds + lane * 40 + g * 8) = av;
        __syncthreads();
        float4 p0 = *(const float4*)(srow + kc);
        float4 p1 = *(const float4*)(srow + kc + 4);
        bf16x8_t b;
        b[0] = (__bf16)p0.x; b[1] = (__bf16)p0.y; b[2] = (__bf16)p0.z; b[3] = (__bf16)p0.w;
        b[4] = (__bf16)p1.x; b[5] = (__bf16)p1.y; b[6] = (__bf16)p1.z; b[7] = (__bf16)p1.w;
        bf16x8_t a0 = *(const bf16x8_t*)(Alds + (col)      * 40 + quad * 8);
        bf16x8_t a1 = *(const bf16x8_t*)(Alds + (16 + col) * 40 + quad * 8);
        bf16x8_t a2 = *(const bf16x8_t*)(Alds + (32 + col) * 40 + quad * 8);
        bf16x8_t a3 = *(const bf16x8_t*)(Alds + (48 + col) * 40 + quad * 8);
        acc0 = MFMA16(a0, b, acc0);
        acc1 = MFMA16(a1, b, acc1);
        acc2 = MFMA16(a2, b, acc2);
        acc3 = MFMA16(a3, b, acc3);
        __syncthreads();
    }
    f32x4_t accs[4] = {acc0, acc1, acc2, acc3};
    float* ob = attnf + (n * IOdim) * Sdim + blockIdx.x * 64 + g * 16 + col;
#pragma unroll
    for (int ai = 0; ai < 4; ai++)
#pragma unroll
        for (int r = 0; r < 4; r++) {
            int i = ai * 16 + quad * 4 + r;
            ob[i * Sdim] = accs[ai][r];
        }
}

// ---------------------------------------------------------------------------
// softmax over s (512) per row; writes bf16 attn. 1 wave per row.
__global__ __launch_bounds__(256) void softmax_kernel(const float* __restrict__ attnf,
                                                      unsigned short* __restrict__ attnb) {
    int row = blockIdx.x * 4 + (threadIdx.x >> 6);
    int lane = threadIdx.x & 63;
    const float* p = attnf + (size_t)row * Sdim + lane * 8;
    float4 v0 = ((const float4*)p)[0];
    float4 v1 = ((const float4*)p)[1];
    float v[8] = {v0.x, v0.y, v0.z, v0.w, v1.x, v1.y, v1.z, v1.w};
    float m = v[0];
#pragma unroll
    for (int j = 1; j < 8; j++) m = fmaxf(m, v[j]);
#pragma unroll
    for (int off = 32; off > 0; off >>= 1) m = fmaxf(m, __shfl_xor(m, off));
    float sum = 0.f;
#pragma unroll
    for (int j = 0; j < 8; j++) { v[j] = __expf(v[j] - m); sum += v[j]; }
#pragma unroll
    for (int off = 32; off > 0; off >>= 1) sum += __shfl_xor(sum, off);
    float inv = 1.0f / sum;
    union { unsigned short u[8]; uint4 q; } res;
#pragma unroll
    for (int j = 0; j < 8; j++) res.u[j] = f2bf(v[j] * inv);
    *(uint4*)(attnb + (size_t)row * Sdim + lane * 8) = res.q;
}

// ---------------------------------------------------------------------------
// mix[n][i][h] = sum_s attn[n][i][s] * states[n][s][h]
// Block: n=blockIdx.y, h-tile 64 (wave -> 16 h), all 64 i. K=s=512 in 32-chunks.
// states chunk transposed to bf16 LDS [h][s]; attn chunk staged to LDS [i][s].
__global__ __launch_bounds__(256) void mix_kernel(const float* __restrict__ states,
                                                  const unsigned short* __restrict__ attnb,
                                                  unsigned short* __restrict__ mixb) {
    __shared__ unsigned short Tlds[64 * 40]; // statesT chunk: [h 64][s 32] stride 40
    __shared__ unsigned short Alds[64 * 40]; // attn chunk:    [i 64][s 32] stride 40
    int n = blockIdx.y, h0 = blockIdx.x * 64;
    int tid = threadIdx.x, lane = tid & 63, g = tid >> 6;
    int col = lane & 15, quad = lane >> 4;
    f32x4_t acc0 = {0,0,0,0}, acc1 = {0,0,0,0}, acc2 = {0,0,0,0}, acc3 = {0,0,0,0};
    for (int sc = 0; sc < Sdim; sc += 32) {
        // stage statesT: thread reads 8 s-rows (g*8+rep) at h=h0+lane (coalesced),
        // packs one 16B LDS write at T[lane][g*8]
        union { unsigned short u[8]; uint4 q; } pk;
#pragma unroll
        for (int rep = 0; rep < 8; rep++) {
            int sl = g * 8 + rep;
            pk.u[rep] = f2bf(states[(n * Sdim + sc + sl) * Hdim + h0 + lane]);
        }
        *(uint4*)(Tlds + lane * 40 + g * 8) = pk.q;
        // stage attn chunk: 16B per thread
        uint4 av = *(const uint4*)(attnb + (n * IOdim + lane) * Sdim + sc + g * 8);
        *(uint4*)(Alds + lane * 40 + g * 8) = av;
        __syncthreads();
        bf16x8_t b  = *(const bf16x8_t*)(Tlds + (g * 16 + col) * 40 + quad * 8);
        bf16x8_t a0 = *(const bf16x8_t*)(Alds + (col)      * 40 + quad * 8);
        bf16x8_t a1 = *(const bf16x8_t*)(Alds + (16 + col) * 40 + quad * 8);
        bf16x8_t a2 = *(const bf16x8_t*)(Alds + (32 + col) * 40 + quad * 8);
        bf16x8_t a3 = *(const bf16x8_t*)(Alds + (48 + col) * 40 + quad * 8);
        acc0 = MFMA16(a0, b, acc0);
        acc1 = MFMA16(a1, b, acc1);
        acc2 = MFMA16(a2, b, acc2);
        acc3 = MFMA16(a3, b, acc3);
        __syncthreads();
    }
    f32x4_t accs[4] = {acc0, acc1, acc2, acc3};
    int h = h0 + g * 16 + col;
#pragma unroll
    for (int ai = 0; ai < 4; ai++)
#pragma unroll
        for (int r = 0; r < 4; r++) {
            int i = ai * 16 + quad * 4 + r;
            mixb[(n * IOdim + i) * Hdim + h] = f2bf(accs[ai][r]);
        }
}

// ---------------------------------------------------------------------------
// o[r][h] = sum_{k<1024} mix[r][k]*Wo[k][h] + sum_{k<1024} outset[r%64][k]*Wo[1024+k][h] + bo[h]
// t = tanh(o) -> bf16.  K=2048 GEMM whose A switches source at k=1024.
// Block: r-tile 64 x h-tile 64; wave -> 16 h cols, 4 row-frags.
__global__ __launch_bounds__(256) void out_gemm(const unsigned short* __restrict__ mixb,
                                                const unsigned short* __restrict__ osb,
                                                const unsigned short* __restrict__ woT,
                                                const float* __restrict__ bo,
                                                unsigned short* __restrict__ tb) {
    __shared__ unsigned short Alds[64 * 40];
    int h0 = blockIdx.x * 64, r0 = blockIdx.y * 64;
    int tid = threadIdx.x, lane = tid & 63, g = tid >> 6;
    int col = lane & 15, quad = lane >> 4;
    f32x4_t acc0 = {0,0,0,0}, acc1 = {0,0,0,0}, acc2 = {0,0,0,0}, acc3 = {0,0,0,0};
    const unsigned short* brow = woT + (h0 + g * 16 + col) * 2048 + quad * 8;
    for (int kc = 0; kc < 2048; kc += 32) {
        int ks = kc + g * 8;
        uint4 av;
        if (ks < 1024) av = *(const uint4*)(mixb + (r0 + lane) * Hdim + ks);
        else           av = *(const uint4*)(osb + lane * Hdim + (ks - 1024));
        *(uint4*)(Alds + lane * 40 + g * 8) = av;
        __syncthreads();
        bf16x8_t b  = *(const bf16x8_t*)(brow + kc);
        bf16x8_t a0 = *(const bf16x8_t*)(Alds + (col)      * 40 + quad * 8);
        bf16x8_t a1 = *(const bf16x8_t*)(Alds + (16 + col) * 40 + quad * 8);
        bf16x8_t a2 = *(const bf16x8_t*)(Alds + (32 + col) * 40 + quad * 8);
        bf16x8_t a3 = *(const bf16x8_t*)(Alds + (48 + col) * 40 + quad * 8);
        acc0 = MFMA16(a0, b, acc0);
        acc1 = MFMA16(a1, b, acc1);
        acc2 = MFMA16(a2, b, acc2);
        acc3 = MFMA16(a3, b, acc3);
        __syncthreads();
    }
    f32x4_t accs[4] = {acc0, acc1, acc2, acc3};
    int h = h0 + g * 16 + col;
    float bov = bo[h];
#pragma unroll
    for (int ai = 0; ai < 4; ai++)
#pragma unroll
        for (int r = 0; r < 4; r++) {
            int rr = r0 + ai * 16 + quad * 4 + r;
            tb[rr * Hdim + h] = f2bf(tanhf(accs[ai][r] + bov));
        }
}

// ---------------------------------------------------------------------------
// final: partial[blk][n][j] = sum_{k in blk-chunk} t[n][k] * Wc[k][j]
// 64 blocks split K=65536; each block does full 64x64 tile over its 1024-k chunk.
__global__ __launch_bounds__(256) void final_gemm(const unsigned short* __restrict__ tb,
                                                  const unsigned short* __restrict__ wcT,
                                                  float* __restrict__ partials) {
    __shared__ unsigned short Alds[64 * 40];
    int kc0 = blockIdx.x * 1024;
    int tid = threadIdx.x, lane = tid & 63, g = tid >> 6;
    int col = lane & 15, quad = lane >> 4;
    f32x4_t acc0 = {0,0,0,0}, acc1 = {0,0,0,0}, acc2 = {0,0,0,0}, acc3 = {0,0,0,0};
    const unsigned short* brow = wcT + (size_t)(g * 16 + col) * 65536 + quad * 8;
    for (int kc = kc0; kc < kc0 + 1024; kc += 32) {
        uint4 av = *(const uint4*)(tb + (size_t)lane * 65536 + kc + g * 8);
        *(uint4*)(Alds + lane * 40 + g * 8) = av;
        __syncthreads();
        bf16x8_t b  = *(const bf16x8_t*)(brow + kc);
        bf16x8_t a0 = *(const bf16x8_t*)(Alds + (col)      * 40 + quad * 8);
        bf16x8_t a1 = *(const bf16x8_t*)(Alds + (16 + col) * 40 + quad * 8);
        bf16x8_t a2 = *(const bf16x8_t*)(Alds + (32 + col) * 40 + quad * 8);
        bf16x8_t a3 = *(const bf16x8_t*)(Alds + (48 + col) * 40 + quad * 8);
        acc0 = MFMA16(a0, b, acc0);
        acc1 = MFMA16(a1, b, acc1);
        acc2 = MFMA16(a2, b, acc2);
        acc3 = MFMA16(a3, b, acc3);
        __syncthreads();
    }
    f32x4_t accs[4] = {acc0, acc1, acc2, acc3};
    int j = g * 16 + col;
    float* pb = partials + blockIdx.x * 4096;
#pragma unroll
    for (int ai = 0; ai < 4; ai++)
#pragma unroll
        for (int r = 0; r < 4; r++) {
            int nn = ai * 16 + quad * 4 + r;
            pb[nn * 64 + j] = accs[ai][r];
        }
}

// reduce 64 partials + bc
__global__ __launch_bounds__(256) void reduce_kernel(const float* __restrict__ partials,
                                                     const float* __restrict__ bc,
                                                     float* __restrict__ out) {
    int idx = blockIdx.x * 256 + threadIdx.x; // 0..4095
    float s = bc[idx & 63];
#pragma unroll 8
    for (int b = 0; b < 64; b++) s += partials[b * 4096 + idx];
    out[idx] = s;
}

// ---------------------------------------------------------------------------
extern "C" void kernel_launch(void* const* d_in, const int* in_sizes, int n_in,
                              void* d_out, int out_size, void* d_ws, size_t ws_size,
                              hipStream_t stream) {
    const float* states     = (const float*)d_in[0]; // [64][512][1024]
    const float* output_set = (const float*)d_in[1]; // [64][1024]
    const float* Wo         = (const float*)d_in[2]; // [2048][1024]
    const float* bo         = (const float*)d_in[3]; // [1024]
    const float* Wc         = (const float*)d_in[4]; // [65536][64]
    const float* bc         = (const float*)d_in[5]; // [64]
    float* out = (float*)d_out;                      // [64][64]

    char* ws = (char*)d_ws;
    // layout (total ~42 MB)
    float*          attnf   = (float*)ws;                                   // 8 MB
    unsigned short* attnb   = (unsigned short*)(ws + (8u  << 20));          // 4 MB
    unsigned short* mixb    = (unsigned short*)(ws + (12u << 20));          // 8 MB
    unsigned short* tb      = (unsigned short*)(ws + (20u << 20));          // 8 MB
    unsigned short* woT     = (unsigned short*)(ws + (28u << 20));          // 4 MB
    unsigned short* osb     = (unsigned short*)(ws + (32u << 20));          // 128 KB
    unsigned short* wcT     = (unsigned short*)(ws + (32u << 20) + (1u << 18)); // 8 MB
    float*          parts   = (float*)(ws + (41u << 20));                   // 1 MB

    cvt_kernel<<<dim3(IOdim * Hdim / 256), dim3(256), 0, stream>>>(output_set, osb, IOdim * Hdim);
    transpose_cvt<<<dim3(Hdim / 32, 2048 / 32), dim3(32, 8), 0, stream>>>(Wo, woT, 2048, Hdim);
    transpose_cvt<<<dim3(64 / 32, 65536 / 32), dim3(32, 8), 0, stream>>>(Wc, wcT, 65536, 64);
    scores_kernel<<<dim3(Sdim / 64, Nbat), dim3(256), 0, stream>>>(states, osb, attnf);
    softmax_kernel<<<dim3(Nbat * IOdim / 4), dim3(256), 0, stream>>>(attnf, attnb);
    mix_kernel<<<dim3(Hdim / 64, Nbat), dim3(256), 0, stream>>>(states, attnb, mixb);
    out_gemm<<<dim3(Hdim / 64, Nbat * IOdim / 64), dim3(256), 0, stream>>>(mixb, osb, woT, bo, tb);
    final_gemm<<<dim3(64), dim3(256), 0, stream>>>(tb, wcT, parts);
    reduce_kernel<<<dim3(16), dim3(256), 0, stream>>>(parts, bc, out);
}